// Round 20
// baseline (874.713 us; speedup 1.0000x reference)
//
#include <hip/hip_runtime.h>
#include <cstddef>
#include <cstdint>

#define NN 20000
#define EE 160000
#define EPRIME 180000   // EE + NN (self loops)
#define GG 128
#define FF 114
#define HH 10
#define HFD 1140        // FF*HH
#define KP 1152         // padded feature dim
#define F1K 2280        // fcg1 K
#define F1KS 18         // split-K chunks
#define F1KC 128        // chunk size
#define NSCB 79         // scan blocks = cdiv(NN,256)

typedef unsigned short ushort_t;
typedef __attribute__((ext_vector_type(8))) short bf16x8;
typedef __attribute__((ext_vector_type(4))) float f32x4;

static constexpr size_t REL  = (size_t)NN * KP;      // [N][KP] region stride (ushorts)
static constexpr size_t ZREL = (size_t)10 * NN * 128; // Z region stride per branch (ushorts)

static inline int cdiv(int a, int b) { return (a + b - 1) / b; }

// ---------------- bf16 helpers ----------------

__device__ __forceinline__ ushort_t f2bf(float v) {
    union { float f; unsigned u; } c; c.f = v;
    unsigned u = c.u;
    unsigned r = (u + 0x7fffu + ((u >> 16) & 1u)) >> 16;   // RNE
    return (ushort_t)r;
}
__device__ __forceinline__ float bf2f(ushort_t h) {
    union { unsigned u; float f; } c; c.u = ((unsigned)h) << 16;
    return c.f;
}

__device__ __forceinline__ void gload16(const void* g, const ushort_t* l) {
    __builtin_amdgcn_global_load_lds(
        (const __attribute__((address_space(1))) unsigned int*)g,
        (__attribute__((address_space(3))) unsigned int*)l, 16, 0, 0);
}

// ---------------- CSR construction (branch = blockIdx.y) ----------------

__global__ void k_init(int* __restrict__ deg, int* __restrict__ gstart, int* __restrict__ gend) {
    int br = blockIdx.y;
    int i = blockIdx.x * blockDim.x + threadIdx.x;
    if (i < NN) deg[br * NN + i] = 1;               // self loop
    if (i < GG) { gstart[br * GG + i] = NN; gend[br * GG + i] = 0; }
}

__global__ void k_count(const int* __restrict__ ei0, const int* __restrict__ ei1,
                        int* __restrict__ deg) {
    int br = blockIdx.y;
    const int* ei = br ? ei1 : ei0;
    int i = blockIdx.x * blockDim.x + threadIdx.x;
    if (i < EE) atomicAdd(&deg[br * NN + ei[EE + i]], 1);
}

__global__ void k_scan1(const int* __restrict__ deg, int* __restrict__ offs, int* __restrict__ bsum) {
    __shared__ int tmp[256];
    int br = blockIdx.y;
    deg += br * NN; offs += br * (NN + 1); bsum += br * 128;
    int b = blockIdx.x, tid = threadIdx.x;
    int i = b * 256 + tid;
    int v = (i < NN) ? deg[i] : 0;
    tmp[tid] = v;
    __syncthreads();
#pragma unroll
    for (int off = 1; off < 256; off <<= 1) {
        int t = (tid >= off) ? tmp[tid - off] : 0;
        __syncthreads();
        tmp[tid] += t;
        __syncthreads();
    }
    if (i < NN) offs[i + 1] = tmp[tid];
    if (tid == 255) bsum[b] = tmp[255];
}

__global__ void k_scan2(int* __restrict__ bsum) {
    __shared__ int tmp[128];
    bsum += blockIdx.y * 128;
    int tid = threadIdx.x;
    int v = (tid < NSCB) ? bsum[tid] : 0;
    tmp[tid] = v;
    __syncthreads();
#pragma unroll
    for (int off = 1; off < 128; off <<= 1) {
        int t = (tid >= off) ? tmp[tid - off] : 0;
        __syncthreads();
        tmp[tid] += t;
        __syncthreads();
    }
    if (tid < NSCB) bsum[tid] = tmp[tid] - v;   // exclusive prefix
}

__global__ void k_scan3prep(int* __restrict__ offs, const int* __restrict__ bsum,
                            int* __restrict__ cursor, const int* __restrict__ deg,
                            float* __restrict__ dinv,
                            const int* __restrict__ batch0, const int* __restrict__ batch1,
                            int* __restrict__ gstart, int* __restrict__ gend) {
    int br = blockIdx.y;
    offs += br * (NN + 1); bsum += br * 128; cursor += br * NN;
    deg += br * NN; dinv += br * NN;
    const int* batch = br ? batch1 : batch0;
    gstart += br * GG; gend += br * GG;
    int i = blockIdx.x * 256 + threadIdx.x;
    if (i < NN) {
        int o = offs[i + 1] + bsum[i >> 8];
        offs[i + 1] = o;
        cursor[i] = o - deg[i];
        dinv[i] = rsqrtf((float)deg[i]);
        int b = batch[i];
        atomicMin(&gstart[b], i);
        atomicMax(&gend[b], i + 1);
    }
    if (i == 0) offs[0] = 0;
}

__global__ void k_fill(const int* __restrict__ ei0, const int* __restrict__ ei1,
                       int* __restrict__ cursor, int* __restrict__ csr) {
    int br = blockIdx.y;
    const int* ei = br ? ei1 : ei0;
    cursor += br * NN; csr += (size_t)br * EPRIME;
    int i = blockIdx.x * blockDim.x + threadIdx.x;
    if (i < EPRIME) {
        int s, d;
        if (i < EE) { s = ei[i]; d = ei[EE + i]; }
        else        { s = i - EE; d = s; }
        int pos = atomicAdd(&cursor[d], 1);
        csr[pos] = s;
    }
}

// ---------------- bf16 conversions ----------------

__global__ void k_split_x(const float* __restrict__ x0, const float* __restrict__ x1,
                          ushort_t* __restrict__ xb) {
    int br = blockIdx.y;
    const float* x = br ? x1 : x0;
    xb += (size_t)br * REL;
    int idx = blockIdx.x * 256 + threadIdx.x;
    if (idx >= NN * 128) return;
    int n = idx >> 7, k = idx & 127;
    float v = (k < FF) ? x[(size_t)n * FF + k] : 0.f;
    xb[idx] = f2bf(v);
}

// gcnW [K,Nc] -> T[n][k]=W[k][n], bf16, zero pad. branch = blockIdx.z
__global__ __launch_bounds__(256) void k_tbf(const float* __restrict__ W0, const float* __restrict__ W1,
                                             int K, int Nc, int Kpad, ushort_t* __restrict__ T) {
    __shared__ float tile[64][65];
    int br = blockIdx.z;
    const float* W = br ? W1 : W0;
    T += (size_t)br * KP * KP;
    int kb = blockIdx.x * 64;
    int nb = blockIdx.y * 64;
    int c = threadIdx.x & 63, r4 = threadIdx.x >> 6;
#pragma unroll
    for (int rr = 0; rr < 16; ++rr) {
        int r = r4 * 16 + rr;
        int gk = kb + r, gn = nb + c;
        tile[r][c] = (gk < K && gn < Nc) ? W[(size_t)gk * Nc + gn] : 0.f;
    }
    __syncthreads();
#pragma unroll
    for (int rr = 0; rr < 16; ++rr) {
        int r = r4 * 16 + rr;
        int gn = nb + r, gk = kb + c;
        T[(size_t)gn * Kpad + gk] = f2bf(tile[c][r]);
    }
}

// per-head gatW block transpose: WgT[br][h][c][k] = gatW[k][h*FF+c], 128x128 bf16, zero pad.
__global__ __launch_bounds__(256) void k_wgtT(const float* __restrict__ W0, const float* __restrict__ W1,
                                              ushort_t* __restrict__ WgT) {
    __shared__ float tile[64][65];
    int y = blockIdx.z;
    int br = y / 10, h = y - 10 * br;
    const float* W = br ? W1 : W0;
    ushort_t* T = WgT + ((size_t)br * 10 + h) * 128 * 128;
    int kb = blockIdx.x * 64, cb = blockIdx.y * 64;
    int c = threadIdx.x & 63, r4 = threadIdx.x >> 6;
#pragma unroll
    for (int rr = 0; rr < 16; ++rr) {
        int r = r4 * 16 + rr;
        int gk = kb + r, gc = cb + c;
        tile[r][c] = (gk < FF && gc < FF) ? W[(size_t)gk * HFD + h * FF + gc] : 0.f;
    }
    __syncthreads();
#pragma unroll
    for (int rr = 0; rr < 16; ++rr) {
        int r = r4 * 16 + rr;
        int gc2 = cb + r, gk2 = kb + c;
        T[(size_t)gc2 * 128 + gk2] = f2bf(tile[c][r]);
    }
}

// Vs/Vd [br][128][10] fp32: Vs[k][h] = sum_f gatW[k][h*FF+f]*att_src[h][f]
__global__ void k_vsd(const float* __restrict__ W0, const float* __restrict__ W1,
                      const float* __restrict__ as0, const float* __restrict__ as1,
                      const float* __restrict__ ad0, const float* __restrict__ ad1,
                      float* __restrict__ Vs, float* __restrict__ Vd) {
    int br = blockIdx.y;
    const float* W = br ? W1 : W0;
    const float* asrc = br ? as1 : as0;
    const float* adst = br ? ad1 : ad0;
    int idx = blockIdx.x * 256 + threadIdx.x;   // k*10+h
    if (idx >= 1280) return;
    int k = idx / 10, h = idx - 10 * (idx / 10);
    float vs = 0.f, vd = 0.f;
    if (k < FF) {
        const float* wrow = W + (size_t)k * HFD + h * FF;
        const float* s = asrc + h * FF;
        const float* d = adst + h * FF;
        for (int f = 0; f < FF; ++f) { vs += wrow[f] * s[f]; vd += wrow[f] * d[f]; }
    }
    Vs[br * 1280 + idx] = vs;
    Vd[br * 1280 + idx] = vd;
}

// attention logits from xb: a_s[n,h] = x[n,:] . Vs[:,h]
__global__ void k_att2(const ushort_t* __restrict__ xbase,
                       const float* __restrict__ Vs, const float* __restrict__ Vd,
                       float* __restrict__ as_, float* __restrict__ ad_) {
    int br = blockIdx.y;
    const ushort_t* xb = xbase + (size_t)br * REL;
    const float* vs = Vs + br * 1280;
    const float* vd = Vd + br * 1280;
    as_ += (size_t)br * NN * HH; ad_ += (size_t)br * NN * HH;
    int id = blockIdx.x * blockDim.x + threadIdx.x;
    if (id >= NN * HH) return;
    int n = id / HH, h = id - HH * (id / HH);
    const ushort_t* row = xb + (size_t)n * 128;
    float as = 0.f, ad = 0.f;
    for (int k = 0; k < FF; k += 2) {
        unsigned qq = *(const unsigned*)(row + k);
        float v0 = bf2f((ushort_t)(qq & 0xffffu));
        float v1 = bf2f((ushort_t)(qq >> 16));
        as += v0 * vs[k * 10 + h] + v1 * vs[(k + 1) * 10 + h];
        ad += v0 * vd[k * 10 + h] + v1 * vd[(k + 1) * 10 + h];
    }
    as_[id] = as;
    ad_[id] = ad;
}

// ---------------- x-domain GAT aggregation: Z[br][h][n][128] bf16 ----------------

template <int NU>
__device__ __forceinline__ void gax_grp(
    int eg, int end, int lane, float my_ad,
    const int* __restrict__ csr, const float* __restrict__ as_,
    const ushort_t* __restrict__ xb,
    float& den, float acc[HH][2]) {
    int s[NU]; float ex[NU];
#pragma unroll
    for (int u = 0; u < NU; ++u) {
        int idx = eg + u; if (idx > end - 1) idx = end - 1;   // clamp (weight zeroed)
        s[u] = csr[idx];
    }
#pragma unroll
    for (int u = 0; u < NU; ++u) {
        float e = 0.f;
        if (lane < HH) {
            float t = as_[s[u] * HH + lane] + my_ad;
            t = (t >= 0.f) ? t : 0.2f * t;
            e = __expf(t);
            if (eg + u >= end) e = 0.f;
        }
        ex[u] = e;
        den += e;
    }
    unsigned xv[NU];
#pragma unroll
    for (int u = 0; u < NU; ++u)
        xv[u] = *(const unsigned*)(xb + (size_t)s[u] * 128 + 2 * lane);
#pragma unroll
    for (int u = 0; u < NU; ++u) {
        float x0 = bf2f((ushort_t)(xv[u] & 0xffffu));
        float x1 = bf2f((ushort_t)(xv[u] >> 16));
#pragma unroll
        for (int h = 0; h < HH; ++h) {
            float w = __shfl(ex[u], h, 64);
            acc[h][0] += w * x0;
            acc[h][1] += w * x1;
        }
    }
}

__global__ __launch_bounds__(256) void gat_aggx(
    const ushort_t* __restrict__ xbase,
    const float* __restrict__ as_, const float* __restrict__ ad_,
    const int* __restrict__ offs, const int* __restrict__ csr,
    ushort_t* __restrict__ Z) {
    int br = blockIdx.y;
    const ushort_t* xb = xbase + (size_t)br * REL;
    as_ += (size_t)br * NN * HH; ad_ += (size_t)br * NN * HH;
    offs += br * (NN + 1); csr += (size_t)br * EPRIME;
    ushort_t* Zb = Z + (size_t)br * ZREL;

    int lane = threadIdx.x & 63;
    int n = blockIdx.x * 4 + (threadIdx.x >> 6);
    if (n >= NN) return;
    int beg = offs[n], end = offs[n + 1];
    float my_ad = (lane < HH) ? ad_[n * HH + lane] : 0.f;

    float den = 0.f;
    float acc[HH][2];
#pragma unroll
    for (int h = 0; h < HH; ++h) { acc[h][0] = 0.f; acc[h][1] = 0.f; }

    int eg = beg;
    for (; eg + 8 <= end; eg += 8)
        gax_grp<8>(eg, end, lane, my_ad, csr, as_, xb, den, acc);
    for (; eg < end; eg += 4)
        gax_grp<4>(eg, end, lane, my_ad, csr, as_, xb, den, acc);

#pragma unroll
    for (int h = 0; h < HH; ++h) {
        float d = __shfl(den, h, 64);
        float inv = 1.f / d;                    // den >= exp(self-loop) > 0
        unsigned pk = (unsigned)f2bf(acc[h][0] * inv)
                    | ((unsigned)f2bf(acc[h][1] * inv) << 16);
        *(unsigned*)(Zb + ((size_t)h * NN + n) * 128 + 2 * lane) = pk;
    }
}

// ---------------- per-head GEMM: h1[:, hFF..hFF+113] = lrelu(Z_h @ WgT_h^T + b) ----------------

__global__ __launch_bounds__(256) void mfma_hgemm(
    const ushort_t* __restrict__ Zbase, const ushort_t* __restrict__ WgT,
    const float* __restrict__ b0, const float* __restrict__ b1,
    ushort_t* __restrict__ Cbase) {
    __shared__ __align__(16) ushort_t lds[2 * 8192];
    int y = blockIdx.y;
    int br = y / 10, h = y - 10 * br;
    const ushort_t* A = Zbase + (size_t)br * ZREL + (size_t)h * NN * 128;
    const ushort_t* Bt = WgT + ((size_t)br * 10 + h) * 128 * 128;
    const float* bias = (br ? b1 : b0) + h * FF;
    ushort_t* Cb = Cbase + (size_t)br * REL;

    const int tid = threadIdx.x;
    const int lane = tid & 63;
    const int w = tid >> 6;
    const int wr = w >> 1, wc = w & 1;

    int nwg = gridDim.x;
    int q = nwg >> 3, r8 = nwg & 7;
    int xcd = blockIdx.x & 7, sidx = blockIdx.x >> 3;
    int wg = (xcd < r8 ? xcd * (q + 1) : r8 * (q + 1) + (xcd - r8) * q) + sidx;

    int row0 = wg * 128; if (row0 > NN - 128) row0 = NN - 128;   // overlap trick

    f32x4 acc[4][4];
#pragma unroll
    for (int i = 0; i < 4; ++i)
#pragma unroll
        for (int j = 0; j < 4; ++j) acc[i][j] = (f32x4){0.f, 0.f, 0.f, 0.f};

    const char* pA[2]; const char* pB[2];
    unsigned ldsoff[2];
#pragma unroll
    for (int i = 0; i < 2; ++i) {
        int c = (w * 2 + i) * 64 + lane;
        int kg = c >> 7, r = c & 127;
        pA[i] = (const char*)A + (size_t)(row0 + r) * 256 + kg * 16;
        pB[i] = (const char*)Bt + (size_t)r * 256 + kg * 16;
        ldsoff[i] = (w * 2 + i) * 512;
    }
    const int kgf = lane >> 4, r15 = lane & 15;

    auto STAGE = [&](int buf, int ks) {
        size_t kb = (size_t)ks * 64;
        unsigned bo = buf ? 8192u : 0u;
#pragma unroll
        for (int i = 0; i < 2; ++i) {
            gload16(pA[i] + kb, lds + bo + 0 + ldsoff[i]);
            gload16(pB[i] + kb, lds + bo + 4096 + ldsoff[i]);
        }
    };

    STAGE(0, 0);
    asm volatile("s_waitcnt vmcnt(0)" ::: "memory");
    __syncthreads();
    int cur = 0;

    for (int ks = 0; ks < 4; ++ks) {
        if (ks + 1 < 4) STAGE(cur ^ 1, ks + 1);
        const ushort_t* lb = lds + (cur ? 8192u : 0u);
        bf16x8 ah[4], bh[4];
#pragma unroll
        for (int i = 0; i < 4; ++i) {
            int ra = wr * 64 + i * 16 + r15;
            int rb = wc * 64 + i * 16 + r15;
            ah[i] = *(const bf16x8*)(lb + 0 + kgf * 1024 + ra * 8);
            bh[i] = *(const bf16x8*)(lb + 4096 + kgf * 1024 + rb * 8);
        }
#pragma unroll
        for (int i = 0; i < 4; ++i)
#pragma unroll
            for (int j = 0; j < 4; ++j)
                acc[i][j] = __builtin_amdgcn_mfma_f32_16x16x32_bf16(ah[i], bh[j], acc[i][j], 0, 0, 0);
        asm volatile("s_waitcnt vmcnt(0)" ::: "memory");
        __syncthreads();
        cur ^= 1;
    }

    const int g4 = lane >> 4;
#pragma unroll
    for (int i = 0; i < 4; ++i)
#pragma unroll
        for (int j = 0; j < 4; ++j) {
            int c = wc * 64 + j * 16 + r15;
#pragma unroll
            for (int reg = 0; reg < 4; ++reg) {
                int r = row0 + wr * 64 + i * 16 + g4 * 4 + reg;
                int gc = h * FF + c;
                if (c < FF) {
                    float v = acc[i][j][reg] + bias[c];
                    v = (v >= 0.f) ? v : 0.01f * v;
                    Cb[(size_t)r * KP + gc] = f2bf(v);
                } else if (h == 9 && gc < KP) {
                    Cb[(size_t)r * KP + gc] = 0;   // zero pad cols 1140..1151
                }
            }
        }
}

// ---------------- full-bf16 MFMA GEMM (h2 = h1 @ gcnW): 256x128 tile, 8 waves, 2-phase dbuf ----------------
// New variant: BM=256 doubles per-barrier MFMA count (128 vs 64) and B-panel L2 reuse.
// Stage = A[4kg][256r][8] (16KB) + B[4kg][128r][8] (8KB) = 24KB; dbuf 48KB; ~70 VGPR ->
// 2 blocks/CU x 8 waves = 16 waves/CU (vs 12 at r18). (r6's BM=256 failure was 144KB/1-block.)

__global__ __launch_bounds__(512) void mfma_gemm(
    const ushort_t* __restrict__ Abase, const ushort_t* __restrict__ Btbase,
    int lda, int ldb, int M, int Nreal, int ksteps, int ncb,
    ushort_t* __restrict__ Cbase, int ldcs) {
    __shared__ __align__(16) ushort_t lds[2 * 12288];   // [buf][A 8192 | B 4096]
    const int br = blockIdx.y;
    const ushort_t* A = Abase + (size_t)br * REL;
    const ushort_t* Bt = Btbase + (size_t)br * KP * KP;
    ushort_t* Cb = Cbase + (size_t)br * ZREL;          // C lives in brA (Z region)

    const int tid = threadIdx.x;
    const int lane = tid & 63;
    const int w = tid >> 6;           // 0..7
    const int wr = w >> 1, wc = w & 1;

    int nwg = gridDim.x;
    int q = nwg >> 3, r8 = nwg & 7;
    int xcd = blockIdx.x & 7, sidx = blockIdx.x >> 3;
    int wg = (xcd < r8 ? xcd * (q + 1) : r8 * (q + 1) + (xcd - r8) * q) + sidx;
    int brow = wg / ncb, bcol = wg - brow * ncb;

    int row0 = brow * 256; if (row0 > M - 256) row0 = M - 256;   // overlap trick
    const int col0 = bcol * 128;

    f32x4 acc[4][4];
#pragma unroll
    for (int i = 0; i < 4; ++i)
#pragma unroll
        for (int j = 0; j < 4; ++j) acc[i][j] = (f32x4){0.f, 0.f, 0.f, 0.f};

    const size_t ldaB = (size_t)lda * 2, ldbB = (size_t)ldb * 2;
    const char* pS[3];
    unsigned ldst[3];
#pragma unroll
    for (int l = 0; l < 3; ++l) {
        int c = l * 512 + tid;            // 16B chunk id 0..1535
        if (c < 1024) { int kg = c >> 8, r = c & 255;
                        pS[l] = (const char*)A + (size_t)(row0 + r) * ldaB + kg * 16; }
        else          { int cc = c - 1024; int kg = cc >> 7, r = cc & 127;
                        pS[l] = (const char*)Bt + (size_t)(col0 + r) * ldbB + kg * 16; }
        ldst[l] = (unsigned)c * 8;        // ushort offset within stage (A at 0, B at 8192)
    }
    const int kgf = lane >> 4, r15 = lane & 15;

    auto STAGE = [&](int buf, int ks) {
        size_t kb = (size_t)ks * 64;
        unsigned bo = buf ? 12288u : 0u;
#pragma unroll
        for (int l = 0; l < 3; ++l)
            gload16(pS[l] + kb, lds + bo + ldst[l]);
    };

    STAGE(0, 0);
    asm volatile("s_waitcnt vmcnt(0)" ::: "memory");
    __syncthreads();
    int cur = 0;

    for (int ks = 0; ks < ksteps; ++ks) {
        if (ks + 1 < ksteps) STAGE(cur ^ 1, ks + 1);   // prefetch flies during MFMA
        const ushort_t* lb = lds + (cur ? 12288u : 0u);
        bf16x8 ah[4], bh[4];
#pragma unroll
        for (int i = 0; i < 4; ++i) {
            int ra = wr * 64 + i * 16 + r15;           // 0..255
            int rb = wc * 64 + i * 16 + r15;           // 0..127
            ah[i] = *(const bf16x8*)(lb + kgf * 2048 + ra * 8);
            bh[i] = *(const bf16x8*)(lb + 8192 + kgf * 1024 + rb * 8);
        }
#pragma unroll
        for (int i = 0; i < 4; ++i)
#pragma unroll
            for (int j = 0; j < 4; ++j)
                acc[i][j] = __builtin_amdgcn_mfma_f32_16x16x32_bf16(ah[i], bh[j], acc[i][j], 0, 0, 0);
        asm volatile("s_waitcnt vmcnt(0)" ::: "memory");
        __syncthreads();
        cur ^= 1;
    }

    const int g4 = lane >> 4;
#pragma unroll
    for (int i = 0; i < 4; ++i)
#pragma unroll
        for (int j = 0; j < 4; ++j) {
            int c = col0 + wc * 64 + j * 16 + r15;
#pragma unroll
            for (int reg = 0; reg < 4; ++reg) {
                int r = row0 + wr * 64 + i * 16 + g4 * 4 + reg;
                if (r < M) {
                    float v = (c < Nreal) ? acc[i][j][reg] : 0.f;
                    Cb[(size_t)r * ldcs + c] = f2bf(v);
                }
            }
        }
}

// ---------------- GCN aggregation: COLUMN-TILED (L2-resident slices) ----------------

template <int NU>
__device__ __forceinline__ void gcn_grp(
    int eg, int end, float di,
    const int* __restrict__ csr, const float* __restrict__ dinv,
    const ushort_t* __restrict__ h2s,   // h2b + k0 (lane's col pair)
    float& a0, float& a1) {
    int s[NU]; float w[NU];
#pragma unroll
    for (int u = 0; u < NU; ++u) {
        int idx = eg + u; if (idx > end - 1) idx = end - 1;   // clamp (weight zeroed)
        s[u] = csr[idx];
    }
#pragma unroll
    for (int u = 0; u < NU; ++u) {
        float ww = dinv[s[u]] * di;
        w[u] = (eg + u < end) ? ww : 0.f;
    }
    unsigned qv[NU];
#pragma unroll
    for (int u = 0; u < NU; ++u)
        qv[u] = *(const unsigned*)(h2s + (size_t)s[u] * KP);
#pragma unroll
    for (int u = 0; u < NU; ++u) {
        a0 += w[u] * bf2f((ushort_t)(qv[u] & 0xffffu));
        a1 += w[u] * bf2f((ushort_t)(qv[u] >> 16));
    }
}

__global__ __launch_bounds__(256) void gcn_agg(
    const ushort_t* __restrict__ h2base, const int* __restrict__ offs, const int* __restrict__ csr,
    const float* __restrict__ dinv,
    const float* __restrict__ b0, const float* __restrict__ b1,
    ushort_t* __restrict__ outbase) {
    int br = blockIdx.z;
    int tile = blockIdx.y;            // 0..8
    const ushort_t* h2b = h2base + (size_t)br * ZREL;   // h2 lives in brA (Z region)
    offs += br * (NN + 1); csr += (size_t)br * EPRIME; dinv += br * NN;
    const float* bias = br ? b1 : b0;
    ushort_t* outb = outbase + (size_t)br * REL;

    int lane = threadIdx.x & 63;
    int n = blockIdx.x * 4 + (threadIdx.x >> 6);
    if (n >= NN) return;
    const int k0 = tile * 128 + 2 * lane;
    const ushort_t* h2s = h2b + k0;
    int beg = offs[n], end = offs[n + 1];
    float di = dinv[n];
    float a0 = 0.f, a1 = 0.f;

    int eg = beg;
    for (; eg + 8 <= end; eg += 8) gcn_grp<8>(eg, end, di, csr, dinv, h2s, a0, a1);
    for (; eg < end; eg += 4)      gcn_grp<4>(eg, end, di, csr, dinv, h2s, a0, a1);

    float v0 = 0.f, v1 = 0.f;
    if (k0 < HFD)     { v0 = a0 + bias[k0];     v0 = (v0 >= 0.f) ? v0 : 0.01f * v0; }
    if (k0 + 1 < HFD) { v1 = a1 + bias[k0 + 1]; v1 = (v1 >= 0.f) ? v1 : 0.01f * v1; }
    unsigned pk = (unsigned)f2bf(v0) | ((unsigned)f2bf(v1) << 16);
    *(unsigned*)(outb + (size_t)n * KP + k0) = pk;
}

// ---------------- graph pooling (max + mean), bf16 input ----------------

__global__ void k_pool(const ushort_t* __restrict__ hbase, const int* __restrict__ gs,
                       const int* __restrict__ ge, float* __restrict__ gpool) {
    int br = blockIdx.z;
    const ushort_t* hfeat = hbase + (size_t)br * REL;
    gs += br * GG; ge += br * GG;
    float* gout = gpool + (size_t)br * GG * 2 * HFD;
    if (threadIdx.x >= 48) return;
    int g = blockIdx.x;
    int mg = blockIdx.y * 48 + threadIdx.x;
    int s = gs[g], e = ge[g];
    int cnt = e - s;
    float mx[8], sm[8];
#pragma unroll
    for (int j = 0; j < 8; ++j) { mx[j] = -1e30f; sm[j] = 0.f; }
    for (int r = s; r < e; ++r) {
        bf16x8 qv = *(const bf16x8*)(hfeat + (size_t)r * KP + 8 * mg);
#pragma unroll
        for (int j = 0; j < 8; ++j) {
            float v = bf2f((ushort_t)qv[j]);
            mx[j] = fmaxf(mx[j], v);
            sm[j] += v;
        }
    }
    float inv = (cnt > 0) ? 1.f / (float)cnt : 0.f;
#pragma unroll
    for (int j = 0; j < 8; ++j) {
        int k = 8 * mg + j;
        if (k < HFD) {
            float m = (cnt > 0) ? mx[j] : 0.f;
            gout[(size_t)g * (2 * HFD) + k] = m;
            gout[(size_t)g * (2 * HFD) + HFD + k] = sm[j] * inv;
        }
    }
}

// ---------------- fcg1 split-K (kt loop MUST stay rolled — round-3 spill regression) ----------------

__global__ __launch_bounds__(256) void k_fcg1_part(
    const float* __restrict__ gpool, const float* __restrict__ B0, const float* __restrict__ B1,
    float* __restrict__ p0, float* __restrict__ p1) {
    __shared__ float As[16][64 + 4];
    __shared__ float Bs[16][64 + 4];
    int br = blockIdx.y >> 1, rowblk = blockIdx.y & 1;
    const float* A = gpool + (size_t)br * GG * F1K;
    const float* B = br ? B1 : B0;
    float* part = br ? p1 : p0;
    int tid = threadIdx.x;
    int tx = tid & 15, ty = tid >> 4;
    int row0 = rowblk * 64, col0 = blockIdx.x * 64;
    int kbeg = blockIdx.z * F1KC;
    float acc[4][4] = {};
#pragma unroll 1
    for (int kt = 0; kt < F1KC / 16; ++kt) {
        int kk = kbeg + kt * 16;
#pragma unroll
        for (int l = 0; l < 4; ++l) {
            int idx = tid + 256 * l;
            int m = idx >> 4, k = idx & 15;
            int gr = row0 + m, gk = kk + k;
            As[k][m] = (gk < F1K) ? A[(size_t)gr * F1K + gk] : 0.f;
        }
#pragma unroll
        for (int l = 0; l < 4; ++l) {
            int idx = tid + 256 * l;
            int nn = idx & 63, k = idx >> 6;
            int gc = col0 + nn, gk = kk + k;
            Bs[k][nn] = (gc < 1000 && gk < F1K) ? B[(size_t)gk * 1000 + gc] : 0.f;
        }
        __syncthreads();
#pragma unroll
        for (int k = 0; k < 16; ++k) {
            float4 av = *(const float4*)&As[k][ty * 4];
            float4 bv = *(const float4*)&Bs[k][tx * 4];
            float a[4] = {av.x, av.y, av.z, av.w};
            float b[4] = {bv.x, bv.y, bv.z, bv.w};
#pragma unroll
            for (int i = 0; i < 4; ++i)
#pragma unroll
                for (int j = 0; j < 4; ++j) acc[i][j] += a[i] * b[j];
        }
        __syncthreads();
    }
    float* pc = part + (size_t)blockIdx.z * GG * 1000;
#pragma unroll
    for (int i = 0; i < 4; ++i) {
        int r = row0 + ty * 4 + i;
#pragma unroll
        for (int j = 0; j < 4; ++j) {
            int c = col0 + tx * 4 + j;
            if (c < 1000) pc[(size_t)r * 1000 + c] = acc[i][j];
        }
    }
}

__global__ void k_fcg1_red(const float* __restrict__ p0, const float* __restrict__ p1,
                           const float* __restrict__ b0, const float* __restrict__ b1,
                           float* __restrict__ fc1out) {
    int br = blockIdx.y;
    const float* part = br ? p1 : p0;
    const float* bias = br ? b1 : b0;
    float* out = fc1out + (size_t)br * GG * 1000;
    int idx = blockIdx.x * 256 + threadIdx.x;
    if (idx >= GG * 1000) return;
    float s = 0.f;
#pragma unroll
    for (int k = 0; k < F1KS; ++k) s += part[(size_t)k * GG * 1000 + idx];
    int n = idx % 1000;
    float v = s + bias[n];
    out[idx] = (v >= 0.f) ? v : 0.01f * v;
}

// ---------------- fcg2 ----------------

__global__ __launch_bounds__(256) void k_fcg2(const float* __restrict__ fc1out,
                                              const float* __restrict__ W0, const float* __restrict__ W1,
                                              const float* __restrict__ b0, const float* __restrict__ b1,
                                              float* __restrict__ bout) {
    __shared__ float part[4][64];
    int br = blockIdx.y;
    const float* in = fc1out + (size_t)br * GG * 1000;
    const float* W = br ? W1 : W0;
    const float* b = br ? b1 : b0;
    float* out = bout + (size_t)br * GG * 64;
    int g = blockIdx.x;
    int o = threadIdx.x & 63, p = threadIdx.x >> 6;
    const float* row = in + (size_t)g * 1000;
    float acc = 0.f;
    for (int k = p * 250; k < (p + 1) * 250; ++k) acc += row[k] * W[k * 64 + o];
    part[p][o] = acc;
    __syncthreads();
    if (p == 0) out[(size_t)g * 64 + o] = part[0][o] + part[1][o] + part[2][o] + part[3][o] + b[o];
}

// ---------------- final head ----------------

__global__ __launch_bounds__(256) void k_final(
    const float* __restrict__ b1, const float* __restrict__ b2, const float* __restrict__ target,
    const float* __restrict__ fcxtW, const float* __restrict__ fcxtb,
    const float* __restrict__ fc1W, const float* __restrict__ fc1b,
    const float* __restrict__ fc2W, const float* __restrict__ fc2b,
    const float* __restrict__ outW, const float* __restrict__ outb,
    float* __restrict__ out) {
    __shared__ float xc[256];
    __shared__ float xt2[128];
    __shared__ float y1[128];
    __shared__ float y2[32];
    int g = blockIdx.x, t = threadIdx.x;
    if (t < 64) xc[t] = b1[(size_t)g * 64 + t];
    else if (t < 128) xc[t] = b2[(size_t)g * 64 + (t - 64)];
    {
        int c = t & 127, p = t >> 7;
        float acc = 0.f;
        const float* trow = target + (size_t)g * 1000;
        for (int k = p * 500; k < (p + 1) * 500; ++k) acc += trow[k] * fcxtW[k * 128 + c];
        if (p == 1) xt2[c] = acc;
        __syncthreads();
        if (p == 0) xc[128 + c] = acc + xt2[c] + fcxtb[c];
    }
    __syncthreads();
    if (t < 128) {
        float acc = 0.f;
        for (int k = 0; k < 256; ++k) acc += xc[k] * fc1W[k * 128 + t];
        acc += fc1b[t];
        y1[t] = (acc >= 0.f) ? acc : 0.01f * acc;
    }
    __syncthreads();
    if (t < 32) {
        float acc = 0.f;
        for (int k = 0; k < 128; ++k) acc += y1[k] * fc2W[k * 32 + t];
        acc += fc2b[t];
        y2[t] = (acc >= 0.f) ? acc : 0.01f * acc;
    }
    __syncthreads();
    if (t == 0) {
        float acc = 0.f;
        for (int k = 0; k < 32; ++k) acc += y2[k] * outW[k];
        out[g] = acc + outb[0];
    }
}

// ---------------- host launch ----------------

extern "C" void kernel_launch(void* const* d_in, const int* in_sizes, int n_in,
                              void* d_out, int out_size, void* d_ws, size_t ws_size,
                              hipStream_t stream) {
    (void)in_sizes; (void)n_in; (void)out_size; (void)ws_size;

    size_t off = 0;
    auto alloc = [&](size_t bytes) -> void* {
        void* p = (char*)d_ws + off;
        off += (bytes + 255) & ~(size_t)255;
        return p;
    };
    char* brA = (char*)alloc(2 * ZREL * 2);   // per-branch: Z -> h2b -> f1part overlays
    char* brB = (char*)alloc(2 * REL * 2);    // per-branch: xb -> h1b -> hgcnb overlays
    ushort_t* Bt  = (ushort_t*)alloc(2 * (size_t)KP * KP * 2);
    ushort_t* WgT = (ushort_t*)alloc(20 * (size_t)128 * 128 * 2);
    float* Vs     = (float*)alloc(2 * 1280 * 4);
    float* Vd     = (float*)alloc(2 * 1280 * 4);
    float* a_s    = (float*)alloc(2 * (size_t)NN * HH * 4);
    float* a_d    = (float*)alloc(2 * (size_t)NN * HH * 4);
    int*   deg    = (int*)alloc(2 * (size_t)NN * 4);
    int*   offs   = (int*)alloc(2 * (size_t)(NN + 1) * 4);
    int*   cursor = (int*)alloc(2 * (size_t)NN * 4);
    int*   csr    = (int*)alloc(2 * (size_t)EPRIME * 4);
    float* dinv   = (float*)alloc(2 * (size_t)NN * 4);
    int*   gstart = (int*)alloc(2 * (size_t)GG * 4);
    int*   gend   = (int*)alloc(2 * (size_t)GG * 4);
    int*   bsum   = (int*)alloc(2 * (size_t)128 * 4);
    float* gpool  = (float*)alloc(2 * (size_t)GG * 2 * HFD * 4);
    float* fc1out = (float*)alloc(2 * (size_t)GG * 1000 * 4);
    float* bout   = (float*)alloc(2 * (size_t)GG * 64 * 4);

    ushort_t* Zb  = (ushort_t*)brA;               // + br*ZREL (overlay: h2b, f1part)
    float* f1p0 = (float*)brA;
    float* f1p1 = (float*)(brA + (size_t)F1KS * GG * 1000 * 4);
    ushort_t* xb  = (ushort_t*)brB;               // + br*REL (overlay: h1b, hgcnb)

    const float* target = (const float*)d_in[6];
    const int NRB = cdiv(NN, 128);        // 157 row blocks (hgemm)
    const int NRB2 = cdiv(NN, 256);       // 79 row blocks (h2 gemm, BM=256)
    const int NCB = KP / 128;             // 9 col blocks

    const float* x0 = (const float*)d_in[0];
    const float* x1 = (const float*)d_in[3];
    const int* ei0 = (const int*)d_in[1];
    const int* ei1 = (const int*)d_in[4];
    const int* batch0 = (const int*)d_in[2];
    const int* batch1 = (const int*)d_in[5];
    const float *gatW0 = (const float*)d_in[7],  *gatW1 = (const float*)d_in[17];
    const float *asrc0 = (const float*)d_in[8],  *asrc1 = (const float*)d_in[18];
    const float *adst0 = (const float*)d_in[9],  *adst1 = (const float*)d_in[19];
    const float *gatb0 = (const float*)d_in[10], *gatb1 = (const float*)d_in[20];
    const float *gcnW0 = (const float*)d_in[11], *gcnW1 = (const float*)d_in[21];
    const float *gcnb0 = (const float*)d_in[12], *gcnb1 = (const float*)d_in[22];
    const float *f1W0  = (const float*)d_in[13], *f1W1  = (const float*)d_in[23];
    const float *f1b0  = (const float*)d_in[14], *f1b1  = (const float*)d_in[24];
    const float *f2W0  = (const float*)d_in[15], *f2W1  = (const float*)d_in[25];
    const float *f2b0  = (const float*)d_in[16], *f2b1  = (const float*)d_in[26];

    // CSR (both branches batched)
    hipLaunchKernelGGL(k_init, dim3(cdiv(NN, 256), 2), dim3(256), 0, stream, deg, gstart, gend);
    hipLaunchKernelGGL(k_count, dim3(cdiv(EE, 256), 2), dim3(256), 0, stream, ei0, ei1, deg);
    hipLaunchKernelGGL(k_scan1, dim3(NSCB, 2), dim3(256), 0, stream, deg, offs, bsum);
    hipLaunchKernelGGL(k_scan2, dim3(1, 2), dim3(128), 0, stream, bsum);
    hipLaunchKernelGGL(k_scan3prep, dim3(NSCB, 2), dim3(256), 0, stream,
                       offs, bsum, cursor, deg, dinv, batch0, batch1, gstart, gend);
    hipLaunchKernelGGL(k_fill, dim3(cdiv(EPRIME, 256), 2), dim3(256), 0, stream, ei0, ei1, cursor, csr);

    // conversions: x -> bf16; per-head gatW^T; Vs/Vd
    hipLaunchKernelGGL(k_split_x, dim3(cdiv(NN * 128, 256), 2), dim3(256), 0, stream, x0, x1, xb);
    hipLaunchKernelGGL(k_wgtT, dim3(2, 2, 20), dim3(256), 0, stream, gatW0, gatW1, WgT);
    hipLaunchKernelGGL(k_vsd, dim3(5, 2), dim3(256), 0, stream,
                       gatW0, gatW1, asrc0, asrc1, adst0, adst1, Vs, Vd);

    // attention logits directly from x
    hipLaunchKernelGGL(k_att2, dim3(cdiv(NN * HH, 256), 2), dim3(256), 0, stream,
                       xb, Vs, Vd, a_s, a_d);

    // x-domain GAT aggregation -> Z (brA)
    hipLaunchKernelGGL(gat_aggx, dim3(cdiv(NN, 4), 2), dim3(256), 0, stream,
                       xb, a_s, a_d, offs, csr, Zb);

    // per-head GEMM: h1 = lrelu(Z_h @ W_h + b)  (writes brB, overwriting xb)
    hipLaunchKernelGGL(mfma_hgemm, dim3(NRB, 20), dim3(256), 0, stream,
                       Zb, WgT, gatb0, gatb1, xb);

    // gcnW -> transpose bf16
    hipLaunchKernelGGL(k_tbf, dim3(KP / 64, KP / 64, 2), dim3(256), 0, stream,
                       gcnW0, gcnW1, HFD, HFD, KP, Bt);

    // h2 = h1 @ gcnW (A = h1b in brB; C = h2b in brA over Z) — 256x128 tile, 8 waves
    hipLaunchKernelGGL(mfma_gemm, dim3(NRB2 * NCB, 2), dim3(512), 0, stream,
                       xb, Bt, KP, KP, NN, HFD, KP / 32, NCB, Zb, KP);

    // GCN aggregate -> hgcn bf16 (brB), column-tiled (L2-resident slices)
    hipLaunchKernelGGL(gcn_agg, dim3(cdiv(NN, 4), 9, 2), dim3(256), 0, stream,
                       Zb, offs, csr, dinv, gcnb0, gcnb1, xb);

    // pooling (bf16 input)
    hipLaunchKernelGGL(k_pool, dim3(GG, 3, 2), dim3(64), 0, stream, xb, gstart, gend, gpool);

    // fcg1 split-K (partials into brA; h2 dead)
    hipLaunchKernelGGL(k_fcg1_part, dim3(16, 4, F1KS), dim3(256), 0, stream,
                       gpool, f1W0, f1W1, f1p0, f1p1);
    hipLaunchKernelGGL(k_fcg1_red, dim3(cdiv(GG * 1000, 256), 2), dim3(256), 0, stream,
                       f1p0, f1p1, f1b0, f1b1, fc1out);

    // fcg2
    hipLaunchKernelGGL(k_fcg2, dim3(GG, 2), dim3(256), 0, stream,
                       fc1out, f2W0, f2W1, f2b0, f2b1, bout);

    hipLaunchKernelGGL(k_final, dim3(GG), dim3(256), 0, stream,
                       bout, bout + (size_t)GG * 64, target,
                       (const float*)d_in[27], (const float*)d_in[28],
                       (const float*)d_in[29], (const float*)d_in[30],
                       (const float*)d_in[31], (const float*)d_in[32],
                       (const float*)d_in[33], (const float*)d_in[34],
                       (float*)d_out);
}

// Round 21
// 829.020 us; speedup vs baseline: 1.0551x; 1.0551x over previous
//
#include <hip/hip_runtime.h>
#include <cstddef>
#include <cstdint>

#define NN 20000
#define EE 160000
#define EPRIME 180000   // EE + NN (self loops)
#define GG 128
#define FF 114
#define HH 10
#define HFD 1140        // FF*HH
#define KP 1152         // padded feature dim
#define F1K 2280        // fcg1 K
#define F1KS 18         // split-K chunks
#define F1KC 128        // chunk size
#define NSCB 79         // scan blocks = cdiv(NN,256)

typedef unsigned short ushort_t;
typedef __attribute__((ext_vector_type(8))) short bf16x8;
typedef __attribute__((ext_vector_type(4))) float f32x4;

static constexpr size_t REL  = (size_t)NN * KP;      // [N][KP] region stride (ushorts)
static constexpr size_t ZREL = (size_t)10 * NN * 128; // Z region stride per branch (ushorts)

static inline int cdiv(int a, int b) { return (a + b - 1) / b; }

// ---------------- bf16 helpers ----------------

__device__ __forceinline__ ushort_t f2bf(float v) {
    union { float f; unsigned u; } c; c.f = v;
    unsigned u = c.u;
    unsigned r = (u + 0x7fffu + ((u >> 16) & 1u)) >> 16;   // RNE
    return (ushort_t)r;
}
__device__ __forceinline__ float bf2f(ushort_t h) {
    union { unsigned u; float f; } c; c.u = ((unsigned)h) << 16;
    return c.f;
}

__device__ __forceinline__ void gload16(const void* g, const ushort_t* l) {
    __builtin_amdgcn_global_load_lds(
        (const __attribute__((address_space(1))) unsigned int*)g,
        (__attribute__((address_space(3))) unsigned int*)l, 16, 0, 0);
}

// ---------------- CSR construction (branch = blockIdx.y) ----------------

__global__ void k_init(int* __restrict__ deg, int* __restrict__ gstart, int* __restrict__ gend) {
    int br = blockIdx.y;
    int i = blockIdx.x * blockDim.x + threadIdx.x;
    if (i < NN) deg[br * NN + i] = 1;               // self loop
    if (i < GG) { gstart[br * GG + i] = NN; gend[br * GG + i] = 0; }
}

__global__ void k_count(const int* __restrict__ ei0, const int* __restrict__ ei1,
                        int* __restrict__ deg) {
    int br = blockIdx.y;
    const int* ei = br ? ei1 : ei0;
    int i = blockIdx.x * blockDim.x + threadIdx.x;
    if (i < EE) atomicAdd(&deg[br * NN + ei[EE + i]], 1);
}

__global__ void k_scan1(const int* __restrict__ deg, int* __restrict__ offs, int* __restrict__ bsum) {
    __shared__ int tmp[256];
    int br = blockIdx.y;
    deg += br * NN; offs += br * (NN + 1); bsum += br * 128;
    int b = blockIdx.x, tid = threadIdx.x;
    int i = b * 256 + tid;
    int v = (i < NN) ? deg[i] : 0;
    tmp[tid] = v;
    __syncthreads();
#pragma unroll
    for (int off = 1; off < 256; off <<= 1) {
        int t = (tid >= off) ? tmp[tid - off] : 0;
        __syncthreads();
        tmp[tid] += t;
        __syncthreads();
    }
    if (i < NN) offs[i + 1] = tmp[tid];
    if (tid == 255) bsum[b] = tmp[255];
}

__global__ void k_scan2(int* __restrict__ bsum) {
    __shared__ int tmp[128];
    bsum += blockIdx.y * 128;
    int tid = threadIdx.x;
    int v = (tid < NSCB) ? bsum[tid] : 0;
    tmp[tid] = v;
    __syncthreads();
#pragma unroll
    for (int off = 1; off < 128; off <<= 1) {
        int t = (tid >= off) ? tmp[tid - off] : 0;
        __syncthreads();
        tmp[tid] += t;
        __syncthreads();
    }
    if (tid < NSCB) bsum[tid] = tmp[tid] - v;   // exclusive prefix
}

__global__ void k_scan3prep(int* __restrict__ offs, const int* __restrict__ bsum,
                            int* __restrict__ cursor, const int* __restrict__ deg,
                            float* __restrict__ dinv,
                            const int* __restrict__ batch0, const int* __restrict__ batch1,
                            int* __restrict__ gstart, int* __restrict__ gend) {
    int br = blockIdx.y;
    offs += br * (NN + 1); bsum += br * 128; cursor += br * NN;
    deg += br * NN; dinv += br * NN;
    const int* batch = br ? batch1 : batch0;
    gstart += br * GG; gend += br * GG;
    int i = blockIdx.x * 256 + threadIdx.x;
    if (i < NN) {
        int o = offs[i + 1] + bsum[i >> 8];
        offs[i + 1] = o;
        cursor[i] = o - deg[i];
        dinv[i] = rsqrtf((float)deg[i]);
        int b = batch[i];
        atomicMin(&gstart[b], i);
        atomicMax(&gend[b], i + 1);
    }
    if (i == 0) offs[0] = 0;
}

__global__ void k_fill(const int* __restrict__ ei0, const int* __restrict__ ei1,
                       int* __restrict__ cursor, int* __restrict__ csr) {
    int br = blockIdx.y;
    const int* ei = br ? ei1 : ei0;
    cursor += br * NN; csr += (size_t)br * EPRIME;
    int i = blockIdx.x * blockDim.x + threadIdx.x;
    if (i < EPRIME) {
        int s, d;
        if (i < EE) { s = ei[i]; d = ei[EE + i]; }
        else        { s = i - EE; d = s; }
        int pos = atomicAdd(&cursor[d], 1);
        csr[pos] = s;
    }
}

// ---------------- bf16 conversions ----------------

__global__ void k_split_x(const float* __restrict__ x0, const float* __restrict__ x1,
                          ushort_t* __restrict__ xb) {
    int br = blockIdx.y;
    const float* x = br ? x1 : x0;
    xb += (size_t)br * REL;
    int idx = blockIdx.x * 256 + threadIdx.x;
    if (idx >= NN * 128) return;
    int n = idx >> 7, k = idx & 127;
    float v = (k < FF) ? x[(size_t)n * FF + k] : 0.f;
    xb[idx] = f2bf(v);
}

// gcnW [K,Nc] -> T[n][k]=W[k][n], bf16, zero pad. branch = blockIdx.z
__global__ __launch_bounds__(256) void k_tbf(const float* __restrict__ W0, const float* __restrict__ W1,
                                             int K, int Nc, int Kpad, ushort_t* __restrict__ T) {
    __shared__ float tile[64][65];
    int br = blockIdx.z;
    const float* W = br ? W1 : W0;
    T += (size_t)br * KP * KP;
    int kb = blockIdx.x * 64;
    int nb = blockIdx.y * 64;
    int c = threadIdx.x & 63, r4 = threadIdx.x >> 6;
#pragma unroll
    for (int rr = 0; rr < 16; ++rr) {
        int r = r4 * 16 + rr;
        int gk = kb + r, gn = nb + c;
        tile[r][c] = (gk < K && gn < Nc) ? W[(size_t)gk * Nc + gn] : 0.f;
    }
    __syncthreads();
#pragma unroll
    for (int rr = 0; rr < 16; ++rr) {
        int r = r4 * 16 + rr;
        int gn = nb + r, gk = kb + c;
        T[(size_t)gn * Kpad + gk] = f2bf(tile[c][r]);
    }
}

// per-head gatW block transpose: WgT[br][h][c][k] = gatW[k][h*FF+c], 128x128 bf16, zero pad.
__global__ __launch_bounds__(256) void k_wgtT(const float* __restrict__ W0, const float* __restrict__ W1,
                                              ushort_t* __restrict__ WgT) {
    __shared__ float tile[64][65];
    int y = blockIdx.z;
    int br = y / 10, h = y - 10 * br;
    const float* W = br ? W1 : W0;
    ushort_t* T = WgT + ((size_t)br * 10 + h) * 128 * 128;
    int kb = blockIdx.x * 64, cb = blockIdx.y * 64;
    int c = threadIdx.x & 63, r4 = threadIdx.x >> 6;
#pragma unroll
    for (int rr = 0; rr < 16; ++rr) {
        int r = r4 * 16 + rr;
        int gk = kb + r, gc = cb + c;
        tile[r][c] = (gk < FF && gc < FF) ? W[(size_t)gk * HFD + h * FF + gc] : 0.f;
    }
    __syncthreads();
#pragma unroll
    for (int rr = 0; rr < 16; ++rr) {
        int r = r4 * 16 + rr;
        int gc2 = cb + r, gk2 = kb + c;
        T[(size_t)gc2 * 128 + gk2] = f2bf(tile[c][r]);
    }
}

// Vs/Vd [br][128][10] fp32: Vs[k][h] = sum_f gatW[k][h*FF+f]*att_src[h][f]
__global__ void k_vsd(const float* __restrict__ W0, const float* __restrict__ W1,
                      const float* __restrict__ as0, const float* __restrict__ as1,
                      const float* __restrict__ ad0, const float* __restrict__ ad1,
                      float* __restrict__ Vs, float* __restrict__ Vd) {
    int br = blockIdx.y;
    const float* W = br ? W1 : W0;
    const float* asrc = br ? as1 : as0;
    const float* adst = br ? ad1 : ad0;
    int idx = blockIdx.x * 256 + threadIdx.x;   // k*10+h
    if (idx >= 1280) return;
    int k = idx / 10, h = idx - 10 * (idx / 10);
    float vs = 0.f, vd = 0.f;
    if (k < FF) {
        const float* wrow = W + (size_t)k * HFD + h * FF;
        const float* s = asrc + h * FF;
        const float* d = adst + h * FF;
        for (int f = 0; f < FF; ++f) { vs += wrow[f] * s[f]; vd += wrow[f] * d[f]; }
    }
    Vs[br * 1280 + idx] = vs;
    Vd[br * 1280 + idx] = vd;
}

// attention logits from xb: a_s[n,h] = x[n,:] . Vs[:,h]
__global__ void k_att2(const ushort_t* __restrict__ xbase,
                       const float* __restrict__ Vs, const float* __restrict__ Vd,
                       float* __restrict__ as_, float* __restrict__ ad_) {
    int br = blockIdx.y;
    const ushort_t* xb = xbase + (size_t)br * REL;
    const float* vs = Vs + br * 1280;
    const float* vd = Vd + br * 1280;
    as_ += (size_t)br * NN * HH; ad_ += (size_t)br * NN * HH;
    int id = blockIdx.x * blockDim.x + threadIdx.x;
    if (id >= NN * HH) return;
    int n = id / HH, h = id - HH * (id / HH);
    const ushort_t* row = xb + (size_t)n * 128;
    float as = 0.f, ad = 0.f;
    for (int k = 0; k < FF; k += 2) {
        unsigned qq = *(const unsigned*)(row + k);
        float v0 = bf2f((ushort_t)(qq & 0xffffu));
        float v1 = bf2f((ushort_t)(qq >> 16));
        as += v0 * vs[k * 10 + h] + v1 * vs[(k + 1) * 10 + h];
        ad += v0 * vd[k * 10 + h] + v1 * vd[(k + 1) * 10 + h];
    }
    as_[id] = as;
    ad_[id] = ad;
}

// ---------------- x-domain GAT aggregation: Z[br][h][n][128] bf16 ----------------

template <int NU>
__device__ __forceinline__ void gax_grp(
    int eg, int end, int lane, float my_ad,
    const int* __restrict__ csr, const float* __restrict__ as_,
    const ushort_t* __restrict__ xb,
    float& den, float acc[HH][2]) {
    int s[NU]; float ex[NU];
#pragma unroll
    for (int u = 0; u < NU; ++u) {
        int idx = eg + u; if (idx > end - 1) idx = end - 1;   // clamp (weight zeroed)
        s[u] = csr[idx];
    }
#pragma unroll
    for (int u = 0; u < NU; ++u) {
        float e = 0.f;
        if (lane < HH) {
            float t = as_[s[u] * HH + lane] + my_ad;
            t = (t >= 0.f) ? t : 0.2f * t;
            e = __expf(t);
            if (eg + u >= end) e = 0.f;
        }
        ex[u] = e;
        den += e;
    }
    unsigned xv[NU];
#pragma unroll
    for (int u = 0; u < NU; ++u)
        xv[u] = *(const unsigned*)(xb + (size_t)s[u] * 128 + 2 * lane);
#pragma unroll
    for (int u = 0; u < NU; ++u) {
        float x0 = bf2f((ushort_t)(xv[u] & 0xffffu));
        float x1 = bf2f((ushort_t)(xv[u] >> 16));
#pragma unroll
        for (int h = 0; h < HH; ++h) {
            float w = __shfl(ex[u], h, 64);
            acc[h][0] += w * x0;
            acc[h][1] += w * x1;
        }
    }
}

__global__ __launch_bounds__(256) void gat_aggx(
    const ushort_t* __restrict__ xbase,
    const float* __restrict__ as_, const float* __restrict__ ad_,
    const int* __restrict__ offs, const int* __restrict__ csr,
    ushort_t* __restrict__ Z) {
    int br = blockIdx.y;
    const ushort_t* xb = xbase + (size_t)br * REL;
    as_ += (size_t)br * NN * HH; ad_ += (size_t)br * NN * HH;
    offs += br * (NN + 1); csr += (size_t)br * EPRIME;
    ushort_t* Zb = Z + (size_t)br * ZREL;

    int lane = threadIdx.x & 63;
    int n = blockIdx.x * 4 + (threadIdx.x >> 6);
    if (n >= NN) return;
    int beg = offs[n], end = offs[n + 1];
    float my_ad = (lane < HH) ? ad_[n * HH + lane] : 0.f;

    float den = 0.f;
    float acc[HH][2];
#pragma unroll
    for (int h = 0; h < HH; ++h) { acc[h][0] = 0.f; acc[h][1] = 0.f; }

    int eg = beg;
    for (; eg + 8 <= end; eg += 8)
        gax_grp<8>(eg, end, lane, my_ad, csr, as_, xb, den, acc);
    for (; eg < end; eg += 4)
        gax_grp<4>(eg, end, lane, my_ad, csr, as_, xb, den, acc);

#pragma unroll
    for (int h = 0; h < HH; ++h) {
        float d = __shfl(den, h, 64);
        float inv = 1.f / d;                    // den >= exp(self-loop) > 0
        unsigned pk = (unsigned)f2bf(acc[h][0] * inv)
                    | ((unsigned)f2bf(acc[h][1] * inv) << 16);
        *(unsigned*)(Zb + ((size_t)h * NN + n) * 128 + 2 * lane) = pk;
    }
}

// ---------------- per-head GEMM: h1[:, hFF..hFF+113] = lrelu(Z_h @ WgT_h^T + b) ----------------

__global__ __launch_bounds__(256) void mfma_hgemm(
    const ushort_t* __restrict__ Zbase, const ushort_t* __restrict__ WgT,
    const float* __restrict__ b0, const float* __restrict__ b1,
    ushort_t* __restrict__ Cbase) {
    __shared__ __align__(16) ushort_t lds[2 * 8192];
    int y = blockIdx.y;
    int br = y / 10, h = y - 10 * br;
    const ushort_t* A = Zbase + (size_t)br * ZREL + (size_t)h * NN * 128;
    const ushort_t* Bt = WgT + ((size_t)br * 10 + h) * 128 * 128;
    const float* bias = (br ? b1 : b0) + h * FF;
    ushort_t* Cb = Cbase + (size_t)br * REL;

    const int tid = threadIdx.x;
    const int lane = tid & 63;
    const int w = tid >> 6;
    const int wr = w >> 1, wc = w & 1;

    int nwg = gridDim.x;
    int q = nwg >> 3, r8 = nwg & 7;
    int xcd = blockIdx.x & 7, sidx = blockIdx.x >> 3;
    int wg = (xcd < r8 ? xcd * (q + 1) : r8 * (q + 1) + (xcd - r8) * q) + sidx;

    int row0 = wg * 128; if (row0 > NN - 128) row0 = NN - 128;   // overlap trick

    f32x4 acc[4][4];
#pragma unroll
    for (int i = 0; i < 4; ++i)
#pragma unroll
        for (int j = 0; j < 4; ++j) acc[i][j] = (f32x4){0.f, 0.f, 0.f, 0.f};

    const char* pA[2]; const char* pB[2];
    unsigned ldsoff[2];
#pragma unroll
    for (int i = 0; i < 2; ++i) {
        int c = (w * 2 + i) * 64 + lane;
        int kg = c >> 7, r = c & 127;
        pA[i] = (const char*)A + (size_t)(row0 + r) * 256 + kg * 16;
        pB[i] = (const char*)Bt + (size_t)r * 256 + kg * 16;
        ldsoff[i] = (w * 2 + i) * 512;
    }
    const int kgf = lane >> 4, r15 = lane & 15;

    auto STAGE = [&](int buf, int ks) {
        size_t kb = (size_t)ks * 64;
        unsigned bo = buf ? 8192u : 0u;
#pragma unroll
        for (int i = 0; i < 2; ++i) {
            gload16(pA[i] + kb, lds + bo + 0 + ldsoff[i]);
            gload16(pB[i] + kb, lds + bo + 4096 + ldsoff[i]);
        }
    };

    STAGE(0, 0);
    asm volatile("s_waitcnt vmcnt(0)" ::: "memory");
    __syncthreads();
    int cur = 0;

    for (int ks = 0; ks < 4; ++ks) {
        if (ks + 1 < 4) STAGE(cur ^ 1, ks + 1);
        const ushort_t* lb = lds + (cur ? 8192u : 0u);
        bf16x8 ah[4], bh[4];
#pragma unroll
        for (int i = 0; i < 4; ++i) {
            int ra = wr * 64 + i * 16 + r15;
            int rb = wc * 64 + i * 16 + r15;
            ah[i] = *(const bf16x8*)(lb + 0 + kgf * 1024 + ra * 8);
            bh[i] = *(const bf16x8*)(lb + 4096 + kgf * 1024 + rb * 8);
        }
#pragma unroll
        for (int i = 0; i < 4; ++i)
#pragma unroll
            for (int j = 0; j < 4; ++j)
                acc[i][j] = __builtin_amdgcn_mfma_f32_16x16x32_bf16(ah[i], bh[j], acc[i][j], 0, 0, 0);
        asm volatile("s_waitcnt vmcnt(0)" ::: "memory");
        __syncthreads();
        cur ^= 1;
    }

    const int g4 = lane >> 4;
#pragma unroll
    for (int i = 0; i < 4; ++i)
#pragma unroll
        for (int j = 0; j < 4; ++j) {
            int c = wc * 64 + j * 16 + r15;
#pragma unroll
            for (int reg = 0; reg < 4; ++reg) {
                int r = row0 + wr * 64 + i * 16 + g4 * 4 + reg;
                int gc = h * FF + c;
                if (c < FF) {
                    float v = acc[i][j][reg] + bias[c];
                    v = (v >= 0.f) ? v : 0.01f * v;
                    Cb[(size_t)r * KP + gc] = f2bf(v);
                } else if (h == 9 && gc < KP) {
                    Cb[(size_t)r * KP + gc] = 0;   // zero pad cols 1140..1151
                }
            }
        }
}

// ---------------- full-bf16 MFMA GEMM (h2 = h1 @ gcnW): 3-stage counted-vmcnt ----------------
// (r16/r18/r19-measured ~238us; kernel CLOSED after 8 schedule/tile variants:
//  {252,279,270,250,238,238,328,280} — this 128x128 3-stage config is the floor.)

__global__ __launch_bounds__(256) void mfma_gemm(
    const ushort_t* __restrict__ Abase, const ushort_t* __restrict__ Btbase,
    int lda, int ldb, int M, int Nreal, int ksteps, int ncb,
    ushort_t* __restrict__ Cbase, int ldcs) {
    __shared__ __align__(16) ushort_t lds[3 * 8192];
    const int br = blockIdx.y;
    const ushort_t* A = Abase + (size_t)br * REL;
    const ushort_t* Bt = Btbase + (size_t)br * KP * KP;
    ushort_t* Cb = Cbase + (size_t)br * ZREL;          // C lives in brA (Z region)

    const int tid = threadIdx.x;
    const int lane = tid & 63;
    const int w = tid >> 6;
    const int wr = w >> 1, wc = w & 1;

    int nwg = gridDim.x;
    int q = nwg >> 3, r8 = nwg & 7;
    int xcd = blockIdx.x & 7, sidx = blockIdx.x >> 3;
    int wg = (xcd < r8 ? xcd * (q + 1) : r8 * (q + 1) + (xcd - r8) * q) + sidx;
    int brow = wg / ncb, bcol = wg - brow * ncb;

    int row0 = brow * 128; if (row0 > M - 128) row0 = M - 128;
    const int col0 = bcol * 128;

    f32x4 acc[4][4];
#pragma unroll
    for (int i = 0; i < 4; ++i)
#pragma unroll
        for (int j = 0; j < 4; ++j) acc[i][j] = (f32x4){0.f, 0.f, 0.f, 0.f};

    const size_t ldaB = (size_t)lda * 2, ldbB = (size_t)ldb * 2;
    const char* pA[2]; const char* pB[2];
    unsigned ldsoff[2];
#pragma unroll
    for (int i = 0; i < 2; ++i) {
        int c = (w * 2 + i) * 64 + lane;
        int kg = c >> 7, r = c & 127;
        pA[i] = (const char*)A + (size_t)(row0 + r) * ldaB + kg * 16;
        pB[i] = (const char*)Bt + (size_t)(col0 + r) * ldbB + kg * 16;
        ldsoff[i] = (w * 2 + i) * 512;
    }
    const int kgf = lane >> 4, r15 = lane & 15;

    auto STAGE = [&](int stg, int ks) {
        size_t kb = (size_t)ks * 64;
        unsigned bo = (unsigned)stg * 8192u;
#pragma unroll
        for (int i = 0; i < 2; ++i) {
            gload16(pA[i] + kb, lds + bo + 0 + ldsoff[i]);
            gload16(pB[i] + kb, lds + bo + 4096 + ldsoff[i]);
        }
    };

    STAGE(0, 0);
    STAGE(1, 1);
    asm volatile("s_waitcnt vmcnt(4)" ::: "memory");
    __builtin_amdgcn_s_barrier();
    __builtin_amdgcn_sched_barrier(0);

    for (int ks = 0; ks < ksteps; ++ks) {
        if (ks + 2 < ksteps) STAGE((ks + 2) % 3, ks + 2);
        const ushort_t* lb = lds + (ks % 3) * 8192;
        bf16x8 ah[4], bh[4];
#pragma unroll
        for (int i = 0; i < 4; ++i) {
            int ra = wr * 64 + i * 16 + r15;
            int rb = wc * 64 + i * 16 + r15;
            ah[i] = *(const bf16x8*)(lb + 0 + kgf * 1024 + ra * 8);
            bh[i] = *(const bf16x8*)(lb + 4096 + kgf * 1024 + rb * 8);
        }
#pragma unroll
        for (int i = 0; i < 4; ++i)
#pragma unroll
            for (int j = 0; j < 4; ++j)
                acc[i][j] = __builtin_amdgcn_mfma_f32_16x16x32_bf16(ah[i], bh[j], acc[i][j], 0, 0, 0);
        if (ks + 2 < ksteps) { asm volatile("s_waitcnt vmcnt(4)" ::: "memory"); }
        else                 { asm volatile("s_waitcnt vmcnt(0)" ::: "memory"); }
        __builtin_amdgcn_s_barrier();
        __builtin_amdgcn_sched_barrier(0);
    }

    const int g4 = lane >> 4;
#pragma unroll
    for (int i = 0; i < 4; ++i)
#pragma unroll
        for (int j = 0; j < 4; ++j) {
            int c = col0 + wc * 64 + j * 16 + r15;
#pragma unroll
            for (int reg = 0; reg < 4; ++reg) {
                int r = row0 + wr * 64 + i * 16 + g4 * 4 + reg;
                if (r < M) {
                    float v = (c < Nreal) ? acc[i][j][reg] : 0.f;
                    Cb[(size_t)r * ldcs + c] = f2bf(v);
                }
            }
        }
}

// ---------------- GCN aggregation: COLUMN-TILED (L2-resident slices) ----------------

template <int NU>
__device__ __forceinline__ void gcn_grp(
    int eg, int end, float di,
    const int* __restrict__ csr, const float* __restrict__ dinv,
    const ushort_t* __restrict__ h2s,   // h2b + k0 (lane's col pair)
    float& a0, float& a1) {
    int s[NU]; float w[NU];
#pragma unroll
    for (int u = 0; u < NU; ++u) {
        int idx = eg + u; if (idx > end - 1) idx = end - 1;   // clamp (weight zeroed)
        s[u] = csr[idx];
    }
#pragma unroll
    for (int u = 0; u < NU; ++u) {
        float ww = dinv[s[u]] * di;
        w[u] = (eg + u < end) ? ww : 0.f;
    }
    unsigned qv[NU];
#pragma unroll
    for (int u = 0; u < NU; ++u)
        qv[u] = *(const unsigned*)(h2s + (size_t)s[u] * KP);
#pragma unroll
    for (int u = 0; u < NU; ++u) {
        a0 += w[u] * bf2f((ushort_t)(qv[u] & 0xffffu));
        a1 += w[u] * bf2f((ushort_t)(qv[u] >> 16));
    }
}

__global__ __launch_bounds__(256) void gcn_agg(
    const ushort_t* __restrict__ h2base, const int* __restrict__ offs, const int* __restrict__ csr,
    const float* __restrict__ dinv,
    const float* __restrict__ b0, const float* __restrict__ b1,
    ushort_t* __restrict__ outbase) {
    int br = blockIdx.z;
    int tile = blockIdx.y;            // 0..8
    const ushort_t* h2b = h2base + (size_t)br * ZREL;   // h2 lives in brA (Z region)
    offs += br * (NN + 1); csr += (size_t)br * EPRIME; dinv += br * NN;
    const float* bias = br ? b1 : b0;
    ushort_t* outb = outbase + (size_t)br * REL;

    int lane = threadIdx.x & 63;
    int n = blockIdx.x * 4 + (threadIdx.x >> 6);
    if (n >= NN) return;
    const int k0 = tile * 128 + 2 * lane;
    const ushort_t* h2s = h2b + k0;
    int beg = offs[n], end = offs[n + 1];
    float di = dinv[n];
    float a0 = 0.f, a1 = 0.f;

    int eg = beg;
    for (; eg + 8 <= end; eg += 8) gcn_grp<8>(eg, end, di, csr, dinv, h2s, a0, a1);
    for (; eg < end; eg += 4)      gcn_grp<4>(eg, end, di, csr, dinv, h2s, a0, a1);

    float v0 = 0.f, v1 = 0.f;
    if (k0 < HFD)     { v0 = a0 + bias[k0];     v0 = (v0 >= 0.f) ? v0 : 0.01f * v0; }
    if (k0 + 1 < HFD) { v1 = a1 + bias[k0 + 1]; v1 = (v1 >= 0.f) ? v1 : 0.01f * v1; }
    unsigned pk = (unsigned)f2bf(v0) | ((unsigned)f2bf(v1) << 16);
    *(unsigned*)(outb + (size_t)n * KP + k0) = pk;
}

// ---------------- graph pooling (max + mean), bf16 input ----------------

__global__ void k_pool(const ushort_t* __restrict__ hbase, const int* __restrict__ gs,
                       const int* __restrict__ ge, float* __restrict__ gpool) {
    int br = blockIdx.z;
    const ushort_t* hfeat = hbase + (size_t)br * REL;
    gs += br * GG; ge += br * GG;
    float* gout = gpool + (size_t)br * GG * 2 * HFD;
    if (threadIdx.x >= 48) return;
    int g = blockIdx.x;
    int mg = blockIdx.y * 48 + threadIdx.x;
    int s = gs[g], e = ge[g];
    int cnt = e - s;
    float mx[8], sm[8];
#pragma unroll
    for (int j = 0; j < 8; ++j) { mx[j] = -1e30f; sm[j] = 0.f; }
    for (int r = s; r < e; ++r) {
        bf16x8 qv = *(const bf16x8*)(hfeat + (size_t)r * KP + 8 * mg);
#pragma unroll
        for (int j = 0; j < 8; ++j) {
            float v = bf2f((ushort_t)qv[j]);
            mx[j] = fmaxf(mx[j], v);
            sm[j] += v;
        }
    }
    float inv = (cnt > 0) ? 1.f / (float)cnt : 0.f;
#pragma unroll
    for (int j = 0; j < 8; ++j) {
        int k = 8 * mg + j;
        if (k < HFD) {
            float m = (cnt > 0) ? mx[j] : 0.f;
            gout[(size_t)g * (2 * HFD) + k] = m;
            gout[(size_t)g * (2 * HFD) + HFD + k] = sm[j] * inv;
        }
    }
}

// ---------------- fcg1 split-K (kt loop MUST stay rolled — round-3 spill regression) ----------------

__global__ __launch_bounds__(256) void k_fcg1_part(
    const float* __restrict__ gpool, const float* __restrict__ B0, const float* __restrict__ B1,
    float* __restrict__ p0, float* __restrict__ p1) {
    __shared__ float As[16][64 + 4];
    __shared__ float Bs[16][64 + 4];
    int br = blockIdx.y >> 1, rowblk = blockIdx.y & 1;
    const float* A = gpool + (size_t)br * GG * F1K;
    const float* B = br ? B1 : B0;
    float* part = br ? p1 : p0;
    int tid = threadIdx.x;
    int tx = tid & 15, ty = tid >> 4;
    int row0 = rowblk * 64, col0 = blockIdx.x * 64;
    int kbeg = blockIdx.z * F1KC;
    float acc[4][4] = {};
#pragma unroll 1
    for (int kt = 0; kt < F1KC / 16; ++kt) {
        int kk = kbeg + kt * 16;
#pragma unroll
        for (int l = 0; l < 4; ++l) {
            int idx = tid + 256 * l;
            int m = idx >> 4, k = idx & 15;
            int gr = row0 + m, gk = kk + k;
            As[k][m] = (gk < F1K) ? A[(size_t)gr * F1K + gk] : 0.f;
        }
#pragma unroll
        for (int l = 0; l < 4; ++l) {
            int idx = tid + 256 * l;
            int nn = idx & 63, k = idx >> 6;
            int gc = col0 + nn, gk = kk + k;
            Bs[k][nn] = (gc < 1000 && gk < F1K) ? B[(size_t)gk * 1000 + gc] : 0.f;
        }
        __syncthreads();
#pragma unroll
        for (int k = 0; k < 16; ++k) {
            float4 av = *(const float4*)&As[k][ty * 4];
            float4 bv = *(const float4*)&Bs[k][tx * 4];
            float a[4] = {av.x, av.y, av.z, av.w};
            float b[4] = {bv.x, bv.y, bv.z, bv.w};
#pragma unroll
            for (int i = 0; i < 4; ++i)
#pragma unroll
                for (int j = 0; j < 4; ++j) acc[i][j] += a[i] * b[j];
        }
        __syncthreads();
    }
    float* pc = part + (size_t)blockIdx.z * GG * 1000;
#pragma unroll
    for (int i = 0; i < 4; ++i) {
        int r = row0 + ty * 4 + i;
#pragma unroll
        for (int j = 0; j < 4; ++j) {
            int c = col0 + tx * 4 + j;
            if (c < 1000) pc[(size_t)r * 1000 + c] = acc[i][j];
        }
    }
}

__global__ void k_fcg1_red(const float* __restrict__ p0, const float* __restrict__ p1,
                           const float* __restrict__ b0, const float* __restrict__ b1,
                           float* __restrict__ fc1out) {
    int br = blockIdx.y;
    const float* part = br ? p1 : p0;
    const float* bias = br ? b1 : b0;
    float* out = fc1out + (size_t)br * GG * 1000;
    int idx = blockIdx.x * 256 + threadIdx.x;
    if (idx >= GG * 1000) return;
    float s = 0.f;
#pragma unroll
    for (int k = 0; k < F1KS; ++k) s += part[(size_t)k * GG * 1000 + idx];
    int n = idx % 1000;
    float v = s + bias[n];
    out[idx] = (v >= 0.f) ? v : 0.01f * v;
}

// ---------------- fcg2 ----------------

__global__ __launch_bounds__(256) void k_fcg2(const float* __restrict__ fc1out,
                                              const float* __restrict__ W0, const float* __restrict__ W1,
                                              const float* __restrict__ b0, const float* __restrict__ b1,
                                              float* __restrict__ bout) {
    __shared__ float part[4][64];
    int br = blockIdx.y;
    const float* in = fc1out + (size_t)br * GG * 1000;
    const float* W = br ? W1 : W0;
    const float* b = br ? b1 : b0;
    float* out = bout + (size_t)br * GG * 64;
    int g = blockIdx.x;
    int o = threadIdx.x & 63, p = threadIdx.x >> 6;
    const float* row = in + (size_t)g * 1000;
    float acc = 0.f;
    for (int k = p * 250; k < (p + 1) * 250; ++k) acc += row[k] * W[k * 64 + o];
    part[p][o] = acc;
    __syncthreads();
    if (p == 0) out[(size_t)g * 64 + o] = part[0][o] + part[1][o] + part[2][o] + part[3][o] + b[o];
}

// ---------------- final head ----------------

__global__ __launch_bounds__(256) void k_final(
    const float* __restrict__ b1, const float* __restrict__ b2, const float* __restrict__ target,
    const float* __restrict__ fcxtW, const float* __restrict__ fcxtb,
    const float* __restrict__ fc1W, const float* __restrict__ fc1b,
    const float* __restrict__ fc2W, const float* __restrict__ fc2b,
    const float* __restrict__ outW, const float* __restrict__ outb,
    float* __restrict__ out) {
    __shared__ float xc[256];
    __shared__ float xt2[128];
    __shared__ float y1[128];
    __shared__ float y2[32];
    int g = blockIdx.x, t = threadIdx.x;
    if (t < 64) xc[t] = b1[(size_t)g * 64 + t];
    else if (t < 128) xc[t] = b2[(size_t)g * 64 + (t - 64)];
    {
        int c = t & 127, p = t >> 7;
        float acc = 0.f;
        const float* trow = target + (size_t)g * 1000;
        for (int k = p * 500; k < (p + 1) * 500; ++k) acc += trow[k] * fcxtW[k * 128 + c];
        if (p == 1) xt2[c] = acc;
        __syncthreads();
        if (p == 0) xc[128 + c] = acc + xt2[c] + fcxtb[c];
    }
    __syncthreads();
    if (t < 128) {
        float acc = 0.f;
        for (int k = 0; k < 256; ++k) acc += xc[k] * fc1W[k * 128 + t];
        acc += fc1b[t];
        y1[t] = (acc >= 0.f) ? acc : 0.01f * acc;
    }
    __syncthreads();
    if (t < 32) {
        float acc = 0.f;
        for (int k = 0; k < 128; ++k) acc += y1[k] * fc2W[k * 32 + t];
        acc += fc2b[t];
        y2[t] = (acc >= 0.f) ? acc : 0.01f * acc;
    }
    __syncthreads();
    if (t == 0) {
        float acc = 0.f;
        for (int k = 0; k < 32; ++k) acc += y2[k] * outW[k];
        out[g] = acc + outb[0];
    }
}

// ---------------- host launch ----------------

extern "C" void kernel_launch(void* const* d_in, const int* in_sizes, int n_in,
                              void* d_out, int out_size, void* d_ws, size_t ws_size,
                              hipStream_t stream) {
    (void)in_sizes; (void)n_in; (void)out_size; (void)ws_size;

    size_t off = 0;
    auto alloc = [&](size_t bytes) -> void* {
        void* p = (char*)d_ws + off;
        off += (bytes + 255) & ~(size_t)255;
        return p;
    };
    char* brA = (char*)alloc(2 * ZREL * 2);   // per-branch: Z -> h2b -> f1part overlays
    char* brB = (char*)alloc(2 * REL * 2);    // per-branch: xb -> h1b -> hgcnb overlays
    ushort_t* Bt  = (ushort_t*)alloc(2 * (size_t)KP * KP * 2);
    ushort_t* WgT = (ushort_t*)alloc(20 * (size_t)128 * 128 * 2);
    float* Vs     = (float*)alloc(2 * 1280 * 4);
    float* Vd     = (float*)alloc(2 * 1280 * 4);
    float* a_s    = (float*)alloc(2 * (size_t)NN * HH * 4);
    float* a_d    = (float*)alloc(2 * (size_t)NN * HH * 4);
    int*   deg    = (int*)alloc(2 * (size_t)NN * 4);
    int*   offs   = (int*)alloc(2 * (size_t)(NN + 1) * 4);
    int*   cursor = (int*)alloc(2 * (size_t)NN * 4);
    int*   csr    = (int*)alloc(2 * (size_t)EPRIME * 4);
    float* dinv   = (float*)alloc(2 * (size_t)NN * 4);
    int*   gstart = (int*)alloc(2 * (size_t)GG * 4);
    int*   gend   = (int*)alloc(2 * (size_t)GG * 4);
    int*   bsum   = (int*)alloc(2 * (size_t)128 * 4);
    float* gpool  = (float*)alloc(2 * (size_t)GG * 2 * HFD * 4);
    float* fc1out = (float*)alloc(2 * (size_t)GG * 1000 * 4);
    float* bout   = (float*)alloc(2 * (size_t)GG * 64 * 4);

    ushort_t* Zb  = (ushort_t*)brA;               // + br*ZREL (overlay: h2b, f1part)
    float* f1p0 = (float*)brA;
    float* f1p1 = (float*)(brA + (size_t)F1KS * GG * 1000 * 4);
    ushort_t* xb  = (ushort_t*)brB;               // + br*REL (overlay: h1b, hgcnb)

    const float* target = (const float*)d_in[6];
    const int NRB = cdiv(NN, 128);        // 157 row blocks
    const int NCB = KP / 128;             // 9 col blocks

    const float* x0 = (const float*)d_in[0];
    const float* x1 = (const float*)d_in[3];
    const int* ei0 = (const int*)d_in[1];
    const int* ei1 = (const int*)d_in[4];
    const int* batch0 = (const int*)d_in[2];
    const int* batch1 = (const int*)d_in[5];
    const float *gatW0 = (const float*)d_in[7],  *gatW1 = (const float*)d_in[17];
    const float *asrc0 = (const float*)d_in[8],  *asrc1 = (const float*)d_in[18];
    const float *adst0 = (const float*)d_in[9],  *adst1 = (const float*)d_in[19];
    const float *gatb0 = (const float*)d_in[10], *gatb1 = (const float*)d_in[20];
    const float *gcnW0 = (const float*)d_in[11], *gcnW1 = (const float*)d_in[21];
    const float *gcnb0 = (const float*)d_in[12], *gcnb1 = (const float*)d_in[22];
    const float *f1W0  = (const float*)d_in[13], *f1W1  = (const float*)d_in[23];
    const float *f1b0  = (const float*)d_in[14], *f1b1  = (const float*)d_in[24];
    const float *f2W0  = (const float*)d_in[15], *f2W1  = (const float*)d_in[25];
    const float *f2b0  = (const float*)d_in[16], *f2b1  = (const float*)d_in[26];

    // CSR (both branches batched)
    hipLaunchKernelGGL(k_init, dim3(cdiv(NN, 256), 2), dim3(256), 0, stream, deg, gstart, gend);
    hipLaunchKernelGGL(k_count, dim3(cdiv(EE, 256), 2), dim3(256), 0, stream, ei0, ei1, deg);
    hipLaunchKernelGGL(k_scan1, dim3(NSCB, 2), dim3(256), 0, stream, deg, offs, bsum);
    hipLaunchKernelGGL(k_scan2, dim3(1, 2), dim3(128), 0, stream, bsum);
    hipLaunchKernelGGL(k_scan3prep, dim3(NSCB, 2), dim3(256), 0, stream,
                       offs, bsum, cursor, deg, dinv, batch0, batch1, gstart, gend);
    hipLaunchKernelGGL(k_fill, dim3(cdiv(EPRIME, 256), 2), dim3(256), 0, stream, ei0, ei1, cursor, csr);

    // conversions: x -> bf16; per-head gatW^T; Vs/Vd
    hipLaunchKernelGGL(k_split_x, dim3(cdiv(NN * 128, 256), 2), dim3(256), 0, stream, x0, x1, xb);
    hipLaunchKernelGGL(k_wgtT, dim3(2, 2, 20), dim3(256), 0, stream, gatW0, gatW1, WgT);
    hipLaunchKernelGGL(k_vsd, dim3(5, 2), dim3(256), 0, stream,
                       gatW0, gatW1, asrc0, asrc1, adst0, adst1, Vs, Vd);

    // attention logits directly from x
    hipLaunchKernelGGL(k_att2, dim3(cdiv(NN * HH, 256), 2), dim3(256), 0, stream,
                       xb, Vs, Vd, a_s, a_d);

    // x-domain GAT aggregation -> Z (brA)
    hipLaunchKernelGGL(gat_aggx, dim3(cdiv(NN, 4), 2), dim3(256), 0, stream,
                       xb, a_s, a_d, offs, csr, Zb);

    // per-head GEMM: h1 = lrelu(Z_h @ W_h + b)  (writes brB, overwriting xb)
    hipLaunchKernelGGL(mfma_hgemm, dim3(NRB, 20), dim3(256), 0, stream,
                       Zb, WgT, gatb0, gatb1, xb);

    // gcnW -> transpose bf16
    hipLaunchKernelGGL(k_tbf, dim3(KP / 64, KP / 64, 2), dim3(256), 0, stream,
                       gcnW0, gcnW1, HFD, HFD, KP, Bt);

    // h2 = h1 @ gcnW (A = h1b in brB; C = h2b in brA over Z) — 3-stage counted-vmcnt
    hipLaunchKernelGGL(mfma_gemm, dim3(NRB * NCB, 2), dim3(256), 0, stream,
                       xb, Bt, KP, KP, NN, HFD, KP / 32, NCB, Zb, KP);

    // GCN aggregate -> hgcn bf16 (brB), column-tiled (L2-resident slices)
    hipLaunchKernelGGL(gcn_agg, dim3(cdiv(NN, 4), 9, 2), dim3(256), 0, stream,
                       Zb, offs, csr, dinv, gcnb0, gcnb1, xb);

    // pooling (bf16 input)
    hipLaunchKernelGGL(k_pool, dim3(GG, 3, 2), dim3(64), 0, stream, xb, gstart, gend, gpool);

    // fcg1 split-K (partials into brA; h2 dead)
    hipLaunchKernelGGL(k_fcg1_part, dim3(16, 4, F1KS), dim3(256), 0, stream,
                       gpool, f1W0, f1W1, f1p0, f1p1);
    hipLaunchKernelGGL(k_fcg1_red, dim3(cdiv(GG * 1000, 256), 2), dim3(256), 0, stream,
                       f1p0, f1p1, f1b0, f1b1, fc1out);

    // fcg2
    hipLaunchKernelGGL(k_fcg2, dim3(GG, 2), dim3(256), 0, stream,
                       fc1out, f2W0, f2W1, f2b0, f2b1, bout);

    hipLaunchKernelGGL(k_final, dim3(GG), dim3(256), 0, stream,
                       bout, bout + (size_t)GG * 64, target,
                       (const float*)d_in[27], (const float*)d_in[28],
                       (const float*)d_in[29], (const float*)d_in[30],
                       (const float*)d_in[31], (const float*)d_in[32],
                       (const float*)d_in[33], (const float*)d_in[34],
                       (float*)d_out);
}